// Round 5
// baseline (956.671 us; speedup 1.0000x reference)
//
#include <hip/hip_runtime.h>
#include <math.h>

#define BATCH 8
#define GB 4              // batches per group (2 groups)
#define CDIM 512
#define HGT 96
#define WID 96
#define HWN (HGT*WID)     // 9216
#define INNER 256
#define NHEADS 8
#define DH 32
#define NPIX (BATCH*HWN)
#define EPSLN 1e-5f
#define QSCALE 0.17677669529663687f
#define PATHSZ ((size_t)GB*INNER*HWN)   // 9,437,184 elements per qkv plane per group

typedef __bf16 bf16_t;
typedef bf16_t bf16x8 __attribute__((ext_vector_type(8)));
typedef float  f32x4  __attribute__((ext_vector_type(4)));

__device__ __forceinline__ void load_lds16(const bf16_t* gp, bf16_t* lp) {
    __builtin_amdgcn_global_load_lds(
        (const __attribute__((address_space(1))) unsigned int*)gp,
        (__attribute__((address_space(3))) unsigned int*)lp,
        16, 0, 0);
}

// ---------------- wsum[o] = sum_c W[o][c]*g[c] (fp32, exact algebra for LN fusion) --------------
__global__ __launch_bounds__(256) void wsum_kernel(const float* __restrict__ qw,
                                                   const float* __restrict__ kw,
                                                   const float* __restrict__ vw,
                                                   const float* __restrict__ g,
                                                   float* __restrict__ wsum) {
    int i = blockIdx.x * 256 + threadIdx.x;
    if (i >= 3 * INNER) return;
    const float* w = (i < INNER) ? qw : (i < 2 * INNER) ? kw : vw;
    int o = i % INNER;
    float s = 0.f;
    for (int c = 0; c < CDIM; ++c) s += w[o * CDIM + c] * g[c];
    wsum[i] = s;
}

// ---------------- weight prep: split (w*g) and out_w into bf16 hi/lo planes ---------------------
// WB layout (bf16): [path(q,k,v)][hi/lo][INNER*CDIM].  OWB: [hi/lo][CDIM*INNER].
__global__ __launch_bounds__(256) void wprep_kernel(const float* __restrict__ qw,
                                                    const float* __restrict__ kw,
                                                    const float* __restrict__ vw,
                                                    const float* __restrict__ g,
                                                    const float* __restrict__ ow,
                                                    bf16_t* __restrict__ WB,
                                                    bf16_t* __restrict__ OWB) {
    int i = blockIdx.x * 256 + threadIdx.x;        // 0..524287
    const int PS = INNER * CDIM;                   // 131072
    if (i < 3 * PS) {
        int m = i / PS;
        int idx = i % PS;
        int c = idx % CDIM;
        const float* w = (m == 0) ? qw : (m == 1) ? kw : vw;
        float val = w[idx] * g[c];
        bf16_t h = (bf16_t)val;
        bf16_t l = (bf16_t)(val - (float)h);
        WB[(size_t)(2 * m) * PS + idx] = h;
        WB[(size_t)(2 * m + 1) * PS + idx] = l;
    } else {
        int idx = i - 3 * PS;                      // 0..131071 over [512][256]
        float val = ow[idx];
        bf16_t h = (bf16_t)val;
        bf16_t l = (bf16_t)(val - (float)h);
        OWB[idx] = h;
        OWB[PS + idx] = l;
    }
}

// ---------------- transpose+split+stats: X [bb][c][n] fp32 -> Fh/Fl [bb][n][c] bf16 -------------
// Also accumulates per-pixel sum/sumsq into S1/S2 (LN stats, 8 c-tile contributions per pixel).
__global__ __launch_bounds__(256) void transpose_split_kernel(const float* __restrict__ X,
                                                              bf16_t* __restrict__ Fh,
                                                              bf16_t* __restrict__ Fl,
                                                              float* __restrict__ S1,
                                                              float* __restrict__ S2,
                                                              int pbase) {
    __shared__ float T[64][65];
    __shared__ float Ps[4][64], Ps2[4][64];
    int bb = blockIdx.z;
    int n0 = blockIdx.x * 64;
    int c0 = blockIdx.y * 64;
    const float* Xb = X + ((size_t)bb * CDIM) * HWN;
    int tid = threadIdx.x;
    // ---- vectorized load: f32x4 per lane (16B/lane) ----
    {
        int nl4 = (tid & 15) * 4;
        int cl = tid >> 4;            // 0..15
        #pragma unroll
        for (int it = 0; it < 4; ++it) {
            int cc = cl + 16 * it;
            f32x4 v = *(const f32x4*)&Xb[(size_t)(c0 + cc) * HWN + n0 + nl4];
            T[cc][nl4]     = v.x;
            T[cc][nl4 + 1] = v.y;
            T[cc][nl4 + 2] = v.z;
            T[cc][nl4 + 3] = v.w;
        }
    }
    int tx = tid & 63, ty = tid >> 6;
    __syncthreads();
    // per-pixel partial LN stats over this c-tile (4 threads/pixel)
    {
        float s = 0.f, s2 = 0.f;
        #pragma unroll
        for (int c = ty * 16; c < ty * 16 + 16; ++c) {
            float v = T[c][tx];
            s += v; s2 += v * v;
        }
        Ps[ty][tx] = s; Ps2[ty][tx] = s2;
    }
    __syncthreads();
    if (tid < 64) {
        float a = Ps[0][tid] + Ps[1][tid] + Ps[2][tid] + Ps[3][tid];
        float b = Ps2[0][tid] + Ps2[1][tid] + Ps2[2][tid] + Ps2[3][tid];
        int p = pbase + bb * HWN + n0 + tid;
        atomicAdd(&S1[p], a);
        atomicAdd(&S2[p], b);
    }
    // vectorized bf16x8 writes: 8 threads per n-row, 8 consecutive c each
    int nr = tid >> 3;            // 0..31
    int c8 = (tid & 7) << 3;      // 0..56
    size_t obase = ((size_t)bb * HWN) * CDIM;
    #pragma unroll
    for (int half = 0; half < 2; ++half) {
        int n = nr + 32 * half;
        bf16x8 hv, lv;
        #pragma unroll
        for (int j = 0; j < 8; ++j) {
            float v = T[c8 + j][n];
            bf16_t h = (bf16_t)v;
            hv[j] = h;
            lv[j] = (bf16_t)(v - (float)h);
        }
        size_t off = obase + (size_t)(n0 + n) * CDIM + c0 + c8;
        *(bf16x8*)&Fh[off] = hv;
        *(bf16x8*)&Fl[off] = lv;
    }
}

// ---------------- split-bf16 3-pass MFMA GEMM, A-in-LDS pipeline + B-direct-from-global ---------
// MODE 0 (QKV): grid.y = 6 -> path=y>>1, o-tile=y&1. Epilogue: input-LN from S1/S2 + wsum.
// MODE 1 (conv2): grid.y = MROWS/128. Epilogue: raw store + per-pixel sum/sumsq atomics into S1/S2.
// A (weights) staged via global_load_lds with both-sides XOR swizzle (verified 0 conflicts).
// B (activations) read DIRECTLY from global as 16B/lane gathers: 16 cache lines per wave-inst,
// L1/L2/L3-resident -> halves LDS read+write traffic and LDS footprint (32 KB: 3-4 blocks/CU).
// Counted vmcnt: STAGE = 4 gload_lds per wave; steady-state wait vmcnt(4) (tile t landed, t+1
// in flight); B-loads issued BEFORE STAGE(t+2) so compiler's B-wait is vmcnt(4), not a drain.
template <int KDIM, int MROWS, int MODE>
__global__ __launch_bounds__(256) void mfma_gemm_kernel(const bf16_t* __restrict__ Wbase,
                                                        const bf16_t* __restrict__ Bh,
                                                        const bf16_t* __restrict__ Bl,
                                                        float* __restrict__ S1,
                                                        float* __restrict__ S2,
                                                        const float* __restrict__ wsum,
                                                        int pbase,
                                                        float* __restrict__ Ybase) {
    __shared__ bf16_t sA[2][2][128 * 32];   // [buf][hi/lo] -- A only, 32 KB total
    int bb = blockIdx.z;
    int n0 = blockIdx.x * 128;
    const int PS = INNER * CDIM;     // weight plane (bf16 elements)
    int o0, path;
    const bf16_t *Ah, *Al;
    float* Y;
    if (MODE == 0) {
        path = blockIdx.y >> 1;
        o0 = (blockIdx.y & 1) * 128;
        Ah = Wbase + (size_t)(2 * path) * PS;
        Al = Wbase + (size_t)(2 * path + 1) * PS;
        Y = Ybase + (size_t)path * PATHSZ;
        wsum += path * INNER;
    } else {
        path = 0;
        o0 = blockIdx.y * 128;
        Ah = Wbase;
        Al = Wbase + PS;
        Y = Ybase;
    }
    int tid = threadIdx.x;
    int wv = tid >> 6, ln = tid & 63;
    int wm = wv >> 1, wn = wv & 1;
    int quad = ln >> 4, lm = ln & 15;
    int srow = ln >> 2;
    // pre-swizzled global slot for A staging (both-sides swizzle, rule #21)
    int scol = ((ln & 3) ^ ((ln >> 3) & 3)) * 8;
    // read-side slot: row = <mult of 16> + lm  ->  swz = (lm>>1)&3, invariant over frags
    int qs = (quad ^ ((lm >> 1) & 3)) * 8;

    const bf16_t* Bhb = Bh + ((size_t)bb * HWN) * KDIM;
    const bf16_t* Blb = Bl + ((size_t)bb * HWN) * KDIM;
    // per-thread B row pointers (n_l fixed per j across the K loop)
    const bf16_t* bhr[4];
    const bf16_t* blr[4];
    #pragma unroll
    for (int j = 0; j < 4; ++j) {
        int n_l = n0 + wn * 64 + j * 16 + lm;
        bhr[j] = Bhb + (size_t)n_l * KDIM + quad * 8;
        blr[j] = Blb + (size_t)n_l * KDIM + quad * 8;
    }

    f32x4 acc[4][4] = {};

    const int NT = KDIM / 32;

    auto STAGE = [&](int buf, int t) {
        int c0 = t * 32;
        #pragma unroll
        for (int tt = 0; tt < 2; ++tt) {
            int inst = wv * 2 + tt;
            int row = inst * 16 + srow;
            size_t goA = (size_t)(o0 + row) * KDIM + c0 + scol;
            load_lds16(&Ah[goA], &sA[buf][0][inst * 512]);
            load_lds16(&Al[goA], &sA[buf][1][inst * 512]);
        }
    };

    STAGE(0, 0);
    STAGE(1, 1);

    #pragma unroll 2
    for (int t = 0; t < NT; ++t) {
        int buf = t & 1;
        // wait tile t's 4 staging loads (oldest); tile t+1's 4 stay outstanding
        if (t < NT - 1) asm volatile("s_waitcnt vmcnt(4)" ::: "memory");
        else            asm volatile("s_waitcnt vmcnt(0)" ::: "memory");
        __builtin_amdgcn_sched_barrier(0);
        __builtin_amdgcn_s_barrier();          // all waves: sA buf(t) fully landed
        __builtin_amdgcn_sched_barrier(0);

        // A fragments from LDS (swizzled)
        bf16x8 afh[4], afl[4];
        #pragma unroll
        for (int i = 0; i < 4; ++i) {
            int o_l = wm * 64 + i * 16 + lm;
            afh[i] = *(const bf16x8*)&sA[buf][0][o_l * 32 + qs];
            afl[i] = *(const bf16x8*)&sA[buf][1][o_l * 32 + qs];
        }
        // B fragments direct from global (L1/L2-resident); issued early to fly over barrier
        bf16x8 bfh[4], bfl[4];
        #pragma unroll
        for (int j = 0; j < 4; ++j) {
            bfh[j] = *(const bf16x8*)&bhr[j][t * 32];
            bfl[j] = *(const bf16x8*)&blr[j][t * 32];
        }
        asm volatile("s_waitcnt lgkmcnt(0)" ::: "memory");   // our ds_reads retired
        __builtin_amdgcn_sched_barrier(0);
        __builtin_amdgcn_s_barrier();          // all waves done reading sA buf -> safe to overwrite
        __builtin_amdgcn_sched_barrier(0);

        if (t + 2 < NT) STAGE(buf, t + 2);     // issue next-next tile; lands during MFMA + next read

        __builtin_amdgcn_s_setprio(1);
        #pragma unroll
        for (int i = 0; i < 4; ++i)
            #pragma unroll
            for (int j = 0; j < 4; ++j) {
                acc[i][j] = __builtin_amdgcn_mfma_f32_16x16x32_bf16(afh[i], bfh[j], acc[i][j], 0, 0, 0);
                acc[i][j] = __builtin_amdgcn_mfma_f32_16x16x32_bf16(afh[i], bfl[j], acc[i][j], 0, 0, 0);
                acc[i][j] = __builtin_amdgcn_mfma_f32_16x16x32_bf16(afl[i], bfh[j], acc[i][j], 0, 0, 0);
            }
        __builtin_amdgcn_s_setprio(0);
    }

    float* Yb = Y + ((size_t)bb * MROWS) * HWN;
    __shared__ float Sn[128], Sn2[128];
    if (MODE == 1) {
        if (tid < 128) Sn[tid] = 0.f; else Sn2[tid - 128] = 0.f;
        __syncthreads();
    }
    #pragma unroll
    for (int j = 0; j < 4; ++j) {
        int nl = wn * 64 + j * 16 + lm;
        int n = n0 + nl;
        float mn = 0.f, rs = 0.f;
        if (MODE == 0) {
            int p = pbase + bb * HWN + n;
            float s1 = S1[p], s2 = S2[p];
            mn = s1 * (1.0f / CDIM);
            float var = s2 * (1.0f / CDIM) - mn * mn;
            rs = rsqrtf(var + EPSLN);
        }
        float js = 0.f, js2 = 0.f;
        #pragma unroll
        for (int i = 0; i < 4; ++i) {
            #pragma unroll
            for (int r = 0; r < 4; ++r) {
                int o = o0 + wm * 64 + i * 16 + quad * 4 + r;
                float v = acc[i][j][r];
                if (MODE == 0) v = rs * (v - mn * wsum[o]);
                Yb[(size_t)o * HWN + n] = v;
                if (MODE == 1) { js += v; js2 += v * v; }
            }
        }
        if (MODE == 1) {
            atomicAdd(&Sn[nl], js);
            atomicAdd(&Sn2[nl], js2);
        }
    }
    if (MODE == 1) {
        __syncthreads();
        if (tid < 128) {
            int p = pbase + bb * HWN + n0 + tid;
            atomicAdd(&S1[p], Sn[tid]);
            atomicAdd(&S2[p], Sn2[tid]);
        }
    }
}

// ---------------- merged depthwise 3x3 SAME, 3 paths; k-path fused exp + channel sums -----------
// A3/D3 layout: [path(q,k,v)][bb][c][HWN]. Block (24,8): thread = 2 rows x 4 cols, 4 row-loads
// serve both output rows. Grid: (HGT/16, INNER, 3*GB). No per-thread divisions.
__global__ __launch_bounds__(192) void dwconv_kernel(const float* __restrict__ A3,
                                                     const float* __restrict__ qwd,
                                                     const float* __restrict__ kwd,
                                                     const float* __restrict__ vwd,
                                                     float* __restrict__ D3,
                                                     float* __restrict__ Ssum,
                                                     int bo) {
    int c = blockIdx.y;
    int zz = blockIdx.z;
    int path = zz >> 2;          // GB == 4
    int bb = zz & 3;
    const float* wf = ((path == 0) ? qwd : (path == 1) ? kwd : vwd) + c * 9;
    float w[9];
    #pragma unroll
    for (int j = 0; j < 9; ++j) w[j] = wf[j];   // block-uniform -> scalar loads

    int x0 = threadIdx.x * 4;                        // 0..92
    int y0 = (blockIdx.x * 8 + threadIdx.y) * 2;     // 0..94
    bool hasL = (x0 != 0);
    bool hasR = (x0 != WID - 4);

    const float* bp = A3 + (size_t)path * PATHSZ + (size_t)(bb * INNER + c) * HWN;
    f32x4 r[4];
    float L[4], R[4];
    #pragma unroll
    for (int dy = 0; dy < 4; ++dy) {
        int yy = y0 + dy - 1;
        if ((unsigned)yy < HGT) {
            const float* rp = bp + yy * WID + x0;
            r[dy] = *(const f32x4*)rp;
            L[dy] = hasL ? rp[-1] : 0.f;
            R[dy] = hasR ? rp[4]  : 0.f;
        } else {
            r[dy] = (f32x4){0.f, 0.f, 0.f, 0.f};
            L[dy] = 0.f; R[dy] = 0.f;
        }
    }

    f32x4 o[2];
    #pragma unroll
    for (int orow = 0; orow < 2; ++orow) {
        float a0 = 0.f, a1 = 0.f, a2 = 0.f, a3 = 0.f;
        #pragma unroll
        for (int dy = 0; dy < 3; ++dy) {
            f32x4 cv = r[orow + dy];
            float lf = L[orow + dy], rg = R[orow + dy];
            float w0 = w[3 * dy], w1 = w[3 * dy + 1], w2 = w[3 * dy + 2];
            a0 += lf   * w0 + cv.x * w1 + cv.y * w2;
            a1 += cv.x * w0 + cv.y * w1 + cv.z * w2;
            a2 += cv.y * w0 + cv.z * w1 + cv.w * w2;
            a3 += cv.z * w0 + cv.w * w1 + rg   * w2;
        }
        o[orow] = (f32x4){a0, a1, a2, a3};
    }

    size_t ob = (size_t)path * PATHSZ + (size_t)(bb * INNER + c) * HWN;
    if (path == 1) {
        float s = 0.f;
        #pragma unroll
        for (int orow = 0; orow < 2; ++orow) {
            #pragma unroll
            for (int j = 0; j < 4; ++j) {
                float e = __expf(o[orow][j]);   // no max-subtraction: |k| is O(1), safe in fp32
                o[orow][j] = e;
                s += e;
            }
            *(f32x4*)&D3[ob + (size_t)(y0 + orow) * WID + x0] = o[orow];
        }
        #pragma unroll
        for (int off2 = 32; off2; off2 >>= 1) s += __shfl_down(s, off2);
        __shared__ float red[3];
        int tid = threadIdx.y * 24 + threadIdx.x;
        int lane = tid & 63, wvi = tid >> 6;
        if (lane == 0) red[wvi] = s;
        __syncthreads();
        if (tid == 0)
            atomicAdd(&Ssum[(bo + bb) * INNER + c], red[0] + red[1] + red[2]);
    } else {
        *(f32x4*)&D3[ob + (size_t)y0 * WID + x0] = o[0];
        *(f32x4*)&D3[ob + (size_t)(y0 + 1) * WID + x0] = o[1];
    }
}

// ---------------- context partials: ctxp[bh][seg][d][e] = sum_{n in seg} ek[d][n]*v[e][n] -------
__global__ __launch_bounds__(256) void context_kernel(const float* __restrict__ K,
                                                      const float* __restrict__ V,
                                                      float* __restrict__ ctxp) {
    int seg = blockIdx.x;                    // 0..15
    int bh = blockIdx.y;                     // 0..GB*NHEADS-1
    int bb = bh / NHEADS, h = bh % NHEADS;
    const float* kb = K + ((size_t)bb * INNER + h * DH) * HWN;
    const float* vb = V + ((size_t)bb * INNER + h * DH) * HWN;
    __shared__ float kt[DH][64];
    __shared__ float vt[DH][65];
    int tid = threadIdx.x;
    int e = tid & 31;
    int d0 = tid >> 5;
    float acc[4] = {0.f, 0.f, 0.f, 0.f};
    for (int ch = 0; ch < 9; ++ch) {
        int n0 = seg * 576 + ch * 64;
        __syncthreads();
        #pragma unroll
        for (int j = 0; j < 8; ++j) {
            int idx = tid + 256 * j;
            int d = idx >> 6, nn = idx & 63;
            kt[d][nn] = kb[(size_t)d * HWN + n0 + nn];
            vt[d][nn] = vb[(size_t)d * HWN + n0 + nn];
        }
        __syncthreads();
        for (int nn = 0; nn < 64; ++nn) {
            float vv = vt[e][nn];
            #pragma unroll
            for (int i = 0; i < 4; ++i) acc[i] += kt[d0 + 8 * i][nn] * vv;
        }
    }
    #pragma unroll
    for (int i = 0; i < 4; ++i)
        ctxp[(((size_t)bh * 16 + seg) * DH + d0 + 8 * i) * DH + e] = acc[i];
}

// ---------------- reduce ctxp over segs and fold in 1/sum(exp(k)) per (b, d-channel) ------------
__global__ __launch_bounds__(256) void ctxreduce_kernel(const float* __restrict__ ctxp,
                                                        const float* __restrict__ Ssum,
                                                        int bo,
                                                        float* __restrict__ ctx) {
    int i = blockIdx.x * 256 + threadIdx.x;  // over GB*NHEADS*1024
    int bh = i >> 10, de = i & 1023;
    int d = de >> 5;
    int bb = bh / NHEADS, h = bh % NHEADS;
    float s = 0.f;
    #pragma unroll
    for (int seg = 0; seg < 16; ++seg) s += ctxp[((size_t)bh * 16 + seg) * 1024 + de];
    float S = Ssum[(bo + bb) * INNER + h * DH + d];
    ctx[i] = s / S;
}

// ---------------- fused q-softmax + q@ctx + silu, writes Oh/Ol [bb][n][INNER] bf16 hi/lo --------
__global__ __launch_bounds__(256) void qctx_kernel(const float* __restrict__ Q,
                                                   const float* __restrict__ ctx,
                                                   bf16_t* __restrict__ Oh,
                                                   bf16_t* __restrict__ Ol) {
    int bh = blockIdx.y;
    int bb = bh / NHEADS, h = bh % NHEADS;
    int n = blockIdx.x * 256 + threadIdx.x;
    __shared__ float cs[DH * DH];
    for (int j = threadIdx.x; j < DH * DH; j += 256) cs[j] = ctx[(size_t)bh * DH * DH + j];
    __syncthreads();
    const float* qb = Q + ((size_t)bb * INNER + h * DH) * HWN + n;
    float qv[DH];
    float mx = -1e30f;
    #pragma unroll
    for (int d = 0; d < DH; ++d) { qv[d] = qb[(size_t)d * HWN]; mx = fmaxf(mx, qv[d]); }
    float s = 0.f;
    #pragma unroll
    for (int d = 0; d < DH; ++d) { qv[d] = __expf(qv[d] - mx); s += qv[d]; }
    float inv = QSCALE / s;
    float acc[DH];
    #pragma unroll
    for (int e = 0; e < DH; ++e) acc[e] = 0.f;
    #pragma unroll
    for (int d = 0; d < DH; ++d) {
        float q = qv[d] * inv;
        #pragma unroll
        for (int e = 0; e < DH; ++e) acc[e] += q * cs[d * DH + e];
    }
    size_t ob = ((size_t)bb * HWN + n) * INNER + h * DH;
    bf16x8 hv, lv;
    #pragma unroll
    for (int e8 = 0; e8 < 4; ++e8) {
        #pragma unroll
        for (int e = 0; e < 8; ++e) {
            float x = acc[e8 * 8 + e];
            float sl = x / (1.0f + __expf(-x));   // silu
            bf16_t h = (bf16_t)sl;
            hv[e] = h;
            lv[e] = (bf16_t)(sl - (float)h);
        }
        *(bf16x8*)&Oh[ob + e8 * 8] = hv;
        *(bf16x8*)&Ol[ob + e8 * 8] = lv;
    }
}

// ---------------- final normalize, stats from S1o/S2o accumulated by conv2 epilogue -------------
// float4 vectorized: 4 consecutive n share (bb,c); HWN%4==0 so no boundary crossing.
__global__ __launch_bounds__(256) void norm_kernel(const float* __restrict__ X,
                                                   const float* __restrict__ S1,
                                                   const float* __restrict__ S2,
                                                   const float* __restrict__ g,
                                                   float* __restrict__ out,
                                                   int pbase) {
    size_t i = ((size_t)blockIdx.x * 256 + threadIdx.x) * 4;  // over GB*CDIM*HW
    int n = (int)(i % HWN);
    size_t bc = i / HWN;
    int c = (int)(bc % CDIM);
    int bb = (int)(bc / CDIM);
    int p = pbase + bb * HWN + n;
    f32x4 x  = *(const f32x4*)&X[i];
    f32x4 s1 = *(const f32x4*)&S1[p];
    f32x4 s2 = *(const f32x4*)&S2[p];
    float gc = g[c];
    f32x4 o;
    #pragma unroll
    for (int j = 0; j < 4; ++j) {
        float m = s1[j] * (1.0f / CDIM);
        float var = s2[j] * (1.0f / CDIM) - m * m;
        float rs = rsqrtf(var + EPSLN);
        o[j] = (x[j] - m) * rs * gc;
    }
    *(f32x4*)&out[i] = o;
}

extern "C" void kernel_launch(void* const* d_in, const int* in_sizes, int n_in,
                              void* d_out, int out_size, void* d_ws, size_t ws_size,
                              hipStream_t stream) {
    const float* fmap       = (const float*)d_in[0];
    const float* norm_g     = (const float*)d_in[1];
    const float* q_w1       = (const float*)d_in[2];
    const float* q_wd       = (const float*)d_in[3];
    const float* k_w1       = (const float*)d_in[4];
    const float* k_wd       = (const float*)d_in[5];
    const float* v_w1       = (const float*)d_in[6];
    const float* v_wd       = (const float*)d_in[7];
    const float* out_w      = (const float*)d_in[8];
    const float* out_norm_g = (const float*)d_in[9];
    float* out = (float*)d_out;

    float* ws = (float*)d_ws;
    size_t off = 0;
    auto alloc = [&](size_t n) { float* p = ws + off; off += n; return p; };
    // --- zeroed stats block (contiguous, one memset) ---
    float* S1   = alloc(73728);     // input-LN sum
    float* S2   = alloc(73728);     // input-LN sumsq
    float* S1o  = alloc(73728);     // output-LN sum (conv2 epilogue)
    float* S2o  = alloc(73728);     // output-LN sumsq
    float* Ssum = alloc(2048);      // per (b, inner-chan) sum of exp(k)
    const size_t ZERON = 73728ull * 4 + 2048;     // 296960 floats
    // --- rest ---
    float* wsum = alloc(768);
    bf16_t* WB  = (bf16_t*)alloc(393216);   // qkv weights, [3][hi/lo][131072] bf16
    bf16_t* OWB = (bf16_t*)alloc(131072);   // out_w, [hi/lo][131072] bf16
    float* ctxp = alloc(524288);
    float* ctx  = alloc(32768);
    bf16_t* Fh  = (bf16_t*)alloc(9437184);  // [GB][HWN][CDIM] bf16
    bf16_t* Fl  = (bf16_t*)alloc(9437184);
    float* A3   = alloc(3 * 9437184);       // [path][GB][INNER][HWN] fp32
    float* D3   = alloc(3 * 9437184);       // dwconv out (k-path holds exp)
    bf16_t* Oh  = (bf16_t*)alloc(4718592);  // [GB][HWN][INNER] bf16
    bf16_t* Ol  = (bf16_t*)alloc(4718592);
    float* CONV2 = alloc(18874368);         // [GB][CDIM][HWN] fp32
    // total: ~105.2M floats = 420.8 MB (ws is 576 MiB per harness fill size)

    dim3 blk(256);
    hipMemsetAsync(S1, 0, ZERON * sizeof(float), stream);
    wsum_kernel<<<dim3(3), blk, 0, stream>>>(q_w1, k_w1, v_w1, norm_g, wsum);
    wprep_kernel<<<dim3(2048), blk, 0, stream>>>(q_w1, k_w1, v_w1, norm_g, out_w, WB, OWB);

    for (int g = 0; g < 2; ++g) {
        const float* fmg = fmap + (size_t)g * GB * CDIM * HWN;
        int pbase = g * GB * HWN;
        int bo = g * GB;

        transpose_split_kernel<<<dim3(144, 8, GB), blk, 0, stream>>>(fmg, Fh, Fl, S1, S2, pbase);

        mfma_gemm_kernel<CDIM, INNER, 0><<<dim3(72, 6, GB), blk, 0, stream>>>(
            WB, Fh, Fl, S1, S2, wsum, pbase, A3);

        dwconv_kernel<<<dim3(HGT / 16, INNER, 3 * GB), dim3(24, 8), 0, stream>>>(
            A3, q_wd, k_wd, v_wd, D3, Ssum, bo);

        context_kernel<<<dim3(16, GB * NHEADS), blk, 0, stream>>>(
            D3 + PATHSZ, D3 + 2 * PATHSZ, ctxp);
        ctxreduce_kernel<<<dim3(GB * NHEADS * 1024 / 256), blk, 0, stream>>>(
            ctxp, Ssum, bo, ctx);
        qctx_kernel<<<dim3(HWN / 256, GB * NHEADS), blk, 0, stream>>>(D3, ctx, Oh, Ol);

        mfma_gemm_kernel<INNER, CDIM, 1><<<dim3(72, 4, GB), blk, 0, stream>>>(
            OWB, Oh, Ol, S1o, S2o, nullptr, pbase, CONV2);

        norm_kernel<<<dim3(GB * CDIM * HWN / 1024), blk, 0, stream>>>(
            CONV2, S1o, S2o, out_norm_g, out + (size_t)g * GB * CDIM * HWN, pbase);
    }
}

// Round 6
// 843.827 us; speedup vs baseline: 1.1337x; 1.1337x over previous
//
#include <hip/hip_runtime.h>
#include <math.h>

#define BATCH 8
#define GB 4              // batches per group (2 groups)
#define CDIM 512
#define HGT 96
#define WID 96
#define HWN (HGT*WID)     // 9216
#define INNER 256
#define NHEADS 8
#define DH 32
#define NPIX (BATCH*HWN)
#define EPSLN 1e-5f
#define QSCALE 0.17677669529663687f
#define PATHSZ ((size_t)GB*INNER*HWN)   // 9,437,184 elements per qkv plane per group

typedef __bf16 bf16_t;
typedef bf16_t bf16x8 __attribute__((ext_vector_type(8)));
typedef float  f32x4  __attribute__((ext_vector_type(4)));

__device__ __forceinline__ void load_lds16(const bf16_t* gp, bf16_t* lp) {
    __builtin_amdgcn_global_load_lds(
        (const __attribute__((address_space(1))) unsigned int*)gp,
        (__attribute__((address_space(3))) unsigned int*)lp,
        16, 0, 0);
}

// ---------------- wsum[o] = sum_c W[o][c]*g[c] (fp32, exact algebra for LN fusion) --------------
__global__ __launch_bounds__(256) void wsum_kernel(const float* __restrict__ qw,
                                                   const float* __restrict__ kw,
                                                   const float* __restrict__ vw,
                                                   const float* __restrict__ g,
                                                   float* __restrict__ wsum) {
    int i = blockIdx.x * 256 + threadIdx.x;
    if (i >= 3 * INNER) return;
    const float* w = (i < INNER) ? qw : (i < 2 * INNER) ? kw : vw;
    int o = i % INNER;
    float s = 0.f;
    for (int c = 0; c < CDIM; ++c) s += w[o * CDIM + c] * g[c];
    wsum[i] = s;
}

// ---------------- weight prep: split (w*g) and out_w into bf16 hi/lo planes ---------------------
// WB layout (bf16): [path(q,k,v)][hi/lo][INNER*CDIM].  OWB: [hi/lo][CDIM*INNER].
__global__ __launch_bounds__(256) void wprep_kernel(const float* __restrict__ qw,
                                                    const float* __restrict__ kw,
                                                    const float* __restrict__ vw,
                                                    const float* __restrict__ g,
                                                    const float* __restrict__ ow,
                                                    bf16_t* __restrict__ WB,
                                                    bf16_t* __restrict__ OWB) {
    int i = blockIdx.x * 256 + threadIdx.x;        // 0..524287
    const int PS = INNER * CDIM;                   // 131072
    if (i < 3 * PS) {
        int m = i / PS;
        int idx = i % PS;
        int c = idx % CDIM;
        const float* w = (m == 0) ? qw : (m == 1) ? kw : vw;
        float val = w[idx] * g[c];
        bf16_t h = (bf16_t)val;
        bf16_t l = (bf16_t)(val - (float)h);
        WB[(size_t)(2 * m) * PS + idx] = h;
        WB[(size_t)(2 * m + 1) * PS + idx] = l;
    } else {
        int idx = i - 3 * PS;                      // 0..131071 over [512][256]
        float val = ow[idx];
        bf16_t h = (bf16_t)val;
        bf16_t l = (bf16_t)(val - (float)h);
        OWB[idx] = h;
        OWB[PS + idx] = l;
    }
}

// ---------------- transpose+split+stats: X [bb][c][n] fp32 -> Fh/Fl [bb][n][c] bf16 -------------
// Also accumulates per-pixel sum/sumsq into S1/S2 (LN stats, 8 c-tile contributions per pixel).
__global__ __launch_bounds__(256) void transpose_split_kernel(const float* __restrict__ X,
                                                              bf16_t* __restrict__ Fh,
                                                              bf16_t* __restrict__ Fl,
                                                              float* __restrict__ S1,
                                                              float* __restrict__ S2,
                                                              int pbase) {
    __shared__ float T[64][65];
    __shared__ float Ps[4][64], Ps2[4][64];
    int bb = blockIdx.z;
    int n0 = blockIdx.x * 64;
    int c0 = blockIdx.y * 64;
    const float* Xb = X + ((size_t)bb * CDIM) * HWN;
    int tid = threadIdx.x;
    // ---- vectorized load: f32x4 per lane (16B/lane) ----
    {
        int nl4 = (tid & 15) * 4;
        int cl = tid >> 4;            // 0..15
        #pragma unroll
        for (int it = 0; it < 4; ++it) {
            int cc = cl + 16 * it;
            f32x4 v = *(const f32x4*)&Xb[(size_t)(c0 + cc) * HWN + n0 + nl4];
            T[cc][nl4]     = v.x;
            T[cc][nl4 + 1] = v.y;
            T[cc][nl4 + 2] = v.z;
            T[cc][nl4 + 3] = v.w;
        }
    }
    int tx = tid & 63, ty = tid >> 6;
    __syncthreads();
    // per-pixel partial LN stats over this c-tile (4 threads/pixel)
    {
        float s = 0.f, s2 = 0.f;
        #pragma unroll
        for (int c = ty * 16; c < ty * 16 + 16; ++c) {
            float v = T[c][tx];
            s += v; s2 += v * v;
        }
        Ps[ty][tx] = s; Ps2[ty][tx] = s2;
    }
    __syncthreads();
    if (tid < 64) {
        float a = Ps[0][tid] + Ps[1][tid] + Ps[2][tid] + Ps[3][tid];
        float b = Ps2[0][tid] + Ps2[1][tid] + Ps2[2][tid] + Ps2[3][tid];
        int p = pbase + bb * HWN + n0 + tid;
        atomicAdd(&S1[p], a);
        atomicAdd(&S2[p], b);
    }
    // vectorized bf16x8 writes: 8 threads per n-row, 8 consecutive c each
    int nr = tid >> 3;            // 0..31
    int c8 = (tid & 7) << 3;      // 0..56
    size_t obase = ((size_t)bb * HWN) * CDIM;
    #pragma unroll
    for (int half = 0; half < 2; ++half) {
        int n = nr + 32 * half;
        bf16x8 hv, lv;
        #pragma unroll
        for (int j = 0; j < 8; ++j) {
            float v = T[c8 + j][n];
            bf16_t h = (bf16_t)v;
            hv[j] = h;
            lv[j] = (bf16_t)(v - (float)h);
        }
        size_t off = obase + (size_t)(n0 + n) * CDIM + c0 + c8;
        *(bf16x8*)&Fh[off] = hv;
        *(bf16x8*)&Fl[off] = lv;
    }
}

// ---------------- split-bf16 3-pass MFMA GEMM, 2-deep counted-vmcnt pipeline (T3+T4+T5) ---------
// MODE 0 (QKV): grid.y = 6 -> path=y>>1, o-tile=y&1. Epilogue: input-LN from S1/S2 + wsum.
// MODE 1 (conv2): grid.y = MROWS/128. Epilogue: raw store + per-pixel sum/sumsq atomics into S1/S2.
// LDS XOR-swizzle (T2, rule #21 both-sides): global source slot pre-swizzled so the linear
// global_load_lds dest yields layout slot_lds = slot_g ^ ((row>>1)&3); reads XOR the same term.
// Pipeline invariant: tile t lives in buf(t&1); stage of tile t+2 issued at iter t AFTER
// lgkmcnt(0)+barrier (all reads of buf retired). vmcnt(8) at iter top waits only tile t's 8
// loads (in-order retirement), leaving tile t+1's 8 in flight across the MFMA phase.
template <int KDIM, int MROWS, int MODE>
__global__ __launch_bounds__(256) void mfma_gemm_kernel(const bf16_t* __restrict__ Wbase,
                                                        const bf16_t* __restrict__ Bh,
                                                        const bf16_t* __restrict__ Bl,
                                                        float* __restrict__ S1,
                                                        float* __restrict__ S2,
                                                        const float* __restrict__ wsum,
                                                        int pbase,
                                                        float* __restrict__ Ybase) {
    __shared__ bf16_t sA[2][2][128 * 32];   // [buf][hi/lo]
    __shared__ bf16_t sB[2][2][128 * 32];
    int bb = blockIdx.z;
    int n0 = blockIdx.x * 128;
    const int PS = INNER * CDIM;     // weight plane (bf16 elements)
    int o0, path;
    const bf16_t *Ah, *Al;
    float* Y;
    if (MODE == 0) {
        path = blockIdx.y >> 1;
        o0 = (blockIdx.y & 1) * 128;
        Ah = Wbase + (size_t)(2 * path) * PS;
        Al = Wbase + (size_t)(2 * path + 1) * PS;
        Y = Ybase + (size_t)path * PATHSZ;
        wsum += path * INNER;
    } else {
        path = 0;
        o0 = blockIdx.y * 128;
        Ah = Wbase;
        Al = Wbase + PS;
        Y = Ybase;
    }
    int tid = threadIdx.x;
    int wv = tid >> 6, ln = tid & 63;
    int wm = wv >> 1, wn = wv & 1;
    int quad = ln >> 4, lm = ln & 15;
    int srow = ln >> 2;
    // pre-swizzled global slot: lane's LDS slot is (ln&3); row parity-pair swz = (row>>1)&3 = (ln>>3)&3
    int scol = ((ln & 3) ^ ((ln >> 3) & 3)) * 8;
    // read-side slot: row = <mult of 16> + lm  ->  swz = (lm>>1)&3, invariant over frags
    int qs = (quad ^ ((lm >> 1) & 3)) * 8;

    const bf16_t* Bhb = Bh + ((size_t)bb * HWN) * KDIM;
    const bf16_t* Blb = Bl + ((size_t)bb * HWN) * KDIM;

    f32x4 acc[4][4] = {};

    const int NT = KDIM / 32;

    auto STAGE = [&](int buf, int t) {
        int c0 = t * 32;
        #pragma unroll
        for (int tt = 0; tt < 2; ++tt) {
            int inst = wv * 2 + tt;
            int row = inst * 16 + srow;
            size_t goA = (size_t)(o0 + row) * KDIM + c0 + scol;
            size_t goB = (size_t)(n0 + row) * KDIM + c0 + scol;
            load_lds16(&Ah[goA],  &sA[buf][0][inst * 512]);
            load_lds16(&Al[goA],  &sA[buf][1][inst * 512]);
            load_lds16(&Bhb[goB], &sB[buf][0][inst * 512]);
            load_lds16(&Blb[goB], &sB[buf][1][inst * 512]);
        }
    };

    STAGE(0, 0);
    STAGE(1, 1);

    #pragma unroll 2
    for (int t = 0; t < NT; ++t) {
        int buf = t & 1;
        // wait tile t's 8 loads (oldest); tile t+1's 8 stay outstanding (counted vmcnt)
        if (t < NT - 1) asm volatile("s_waitcnt vmcnt(8)" ::: "memory");
        else            asm volatile("s_waitcnt vmcnt(0)" ::: "memory");
        __builtin_amdgcn_sched_barrier(0);
        __builtin_amdgcn_s_barrier();          // all waves: buf(t) fully landed
        __builtin_amdgcn_sched_barrier(0);

        bf16x8 afh[4], afl[4], bfh[4], bfl[4];
        #pragma unroll
        for (int i = 0; i < 4; ++i) {
            int o_l = wm * 64 + i * 16 + lm;
            afh[i] = *(const bf16x8*)&sA[buf][0][o_l * 32 + qs];
            afl[i] = *(const bf16x8*)&sA[buf][1][o_l * 32 + qs];
            int n_l = wn * 64 + i * 16 + lm;
            bfh[i] = *(const bf16x8*)&sB[buf][0][n_l * 32 + qs];
            bfl[i] = *(const bf16x8*)&sB[buf][1][n_l * 32 + qs];
        }
        asm volatile("s_waitcnt lgkmcnt(0)" ::: "memory");   // our ds_reads retired
        __builtin_amdgcn_sched_barrier(0);
        __builtin_amdgcn_s_barrier();          // all waves done reading buf -> safe to overwrite
        __builtin_amdgcn_sched_barrier(0);

        if (t + 2 < NT) STAGE(buf, t + 2);     // issue next-next tile; lands during MFMA + next read

        __builtin_amdgcn_s_setprio(1);
        #pragma unroll
        for (int i = 0; i < 4; ++i)
            #pragma unroll
            for (int j = 0; j < 4; ++j) {
                acc[i][j] = __builtin_amdgcn_mfma_f32_16x16x32_bf16(afh[i], bfh[j], acc[i][j], 0, 0, 0);
                acc[i][j] = __builtin_amdgcn_mfma_f32_16x16x32_bf16(afh[i], bfl[j], acc[i][j], 0, 0, 0);
                acc[i][j] = __builtin_amdgcn_mfma_f32_16x16x32_bf16(afl[i], bfh[j], acc[i][j], 0, 0, 0);
            }
        __builtin_amdgcn_s_setprio(0);
    }

    float* Yb = Y + ((size_t)bb * MROWS) * HWN;
    __shared__ float Sn[128], Sn2[128];
    if (MODE == 1) {
        if (tid < 128) Sn[tid] = 0.f; else Sn2[tid - 128] = 0.f;
        __syncthreads();
    }
    #pragma unroll
    for (int j = 0; j < 4; ++j) {
        int nl = wn * 64 + j * 16 + lm;
        int n = n0 + nl;
        float mn = 0.f, rs = 0.f;
        if (MODE == 0) {
            int p = pbase + bb * HWN + n;
            float s1 = S1[p], s2 = S2[p];
            mn = s1 * (1.0f / CDIM);
            float var = s2 * (1.0f / CDIM) - mn * mn;
            rs = rsqrtf(var + EPSLN);
        }
        float js = 0.f, js2 = 0.f;
        #pragma unroll
        for (int i = 0; i < 4; ++i) {
            #pragma unroll
            for (int r = 0; r < 4; ++r) {
                int o = o0 + wm * 64 + i * 16 + quad * 4 + r;
                float v = acc[i][j][r];
                if (MODE == 0) v = rs * (v - mn * wsum[o]);
                Yb[(size_t)o * HWN + n] = v;
                if (MODE == 1) { js += v; js2 += v * v; }
            }
        }
        if (MODE == 1) {
            atomicAdd(&Sn[nl], js);
            atomicAdd(&Sn2[nl], js2);
        }
    }
    if (MODE == 1) {
        __syncthreads();
        if (tid < 128) {
            int p = pbase + bb * HWN + n0 + tid;
            atomicAdd(&S1[p], Sn[tid]);
            atomicAdd(&S2[p], Sn2[tid]);
        }
    }
}

// ---------------- merged depthwise 3x3 SAME, 3 paths; k-path fused exp + channel sums -----------
// A3/D3 layout: [path(q,k,v)][bb][c][HWN]. Block (24,8): thread = 2 rows x 4 cols, 4 row-loads
// serve both output rows. Grid: (HGT/16, INNER, 3*GB). No per-thread divisions.
__global__ __launch_bounds__(192) void dwconv_kernel(const float* __restrict__ A3,
                                                     const float* __restrict__ qwd,
                                                     const float* __restrict__ kwd,
                                                     const float* __restrict__ vwd,
                                                     float* __restrict__ D3,
                                                     float* __restrict__ Ssum,
                                                     int bo) {
    int c = blockIdx.y;
    int zz = blockIdx.z;
    int path = zz >> 2;          // GB == 4
    int bb = zz & 3;
    const float* wf = ((path == 0) ? qwd : (path == 1) ? kwd : vwd) + c * 9;
    float w[9];
    #pragma unroll
    for (int j = 0; j < 9; ++j) w[j] = wf[j];   // block-uniform -> scalar loads

    int x0 = threadIdx.x * 4;                        // 0..92
    int y0 = (blockIdx.x * 8 + threadIdx.y) * 2;     // 0..94
    bool hasL = (x0 != 0);
    bool hasR = (x0 != WID - 4);

    const float* bp = A3 + (size_t)path * PATHSZ + (size_t)(bb * INNER + c) * HWN;
    f32x4 r[4];
    float L[4], R[4];
    #pragma unroll
    for (int dy = 0; dy < 4; ++dy) {
        int yy = y0 + dy - 1;
        if ((unsigned)yy < HGT) {
            const float* rp = bp + yy * WID + x0;
            r[dy] = *(const f32x4*)rp;
            L[dy] = hasL ? rp[-1] : 0.f;
            R[dy] = hasR ? rp[4]  : 0.f;
        } else {
            r[dy] = (f32x4){0.f, 0.f, 0.f, 0.f};
            L[dy] = 0.f; R[dy] = 0.f;
        }
    }

    f32x4 o[2];
    #pragma unroll
    for (int orow = 0; orow < 2; ++orow) {
        float a0 = 0.f, a1 = 0.f, a2 = 0.f, a3 = 0.f;
        #pragma unroll
        for (int dy = 0; dy < 3; ++dy) {
            f32x4 cv = r[orow + dy];
            float lf = L[orow + dy], rg = R[orow + dy];
            float w0 = w[3 * dy], w1 = w[3 * dy + 1], w2 = w[3 * dy + 2];
            a0 += lf   * w0 + cv.x * w1 + cv.y * w2;
            a1 += cv.x * w0 + cv.y * w1 + cv.z * w2;
            a2 += cv.y * w0 + cv.z * w1 + cv.w * w2;
            a3 += cv.z * w0 + cv.w * w1 + rg   * w2;
        }
        o[orow] = (f32x4){a0, a1, a2, a3};
    }

    size_t ob = (size_t)path * PATHSZ + (size_t)(bb * INNER + c) * HWN;
    if (path == 1) {
        float s = 0.f;
        #pragma unroll
        for (int orow = 0; orow < 2; ++orow) {
            #pragma unroll
            for (int j = 0; j < 4; ++j) {
                float e = __expf(o[orow][j]);   // no max-subtraction: |k| is O(1), safe in fp32
                o[orow][j] = e;
                s += e;
            }
            *(f32x4*)&D3[ob + (size_t)(y0 + orow) * WID + x0] = o[orow];
        }
        #pragma unroll
        for (int off2 = 32; off2; off2 >>= 1) s += __shfl_down(s, off2);
        __shared__ float red[3];
        int tid = threadIdx.y * 24 + threadIdx.x;
        int lane = tid & 63, wvi = tid >> 6;
        if (lane == 0) red[wvi] = s;
        __syncthreads();
        if (tid == 0)
            atomicAdd(&Ssum[(bo + bb) * INNER + c], red[0] + red[1] + red[2]);
    } else {
        *(f32x4*)&D3[ob + (size_t)y0 * WID + x0] = o[0];
        *(f32x4*)&D3[ob + (size_t)(y0 + 1) * WID + x0] = o[1];
    }
}

// ---------------- context partials: ctxp[bh][seg][d][e] = sum_{n in seg} ek[d][n]*v[e][n] -------
__global__ __launch_bounds__(256) void context_kernel(const float* __restrict__ K,
                                                      const float* __restrict__ V,
                                                      float* __restrict__ ctxp) {
    int seg = blockIdx.x;                    // 0..15
    int bh = blockIdx.y;                     // 0..GB*NHEADS-1
    int bb = bh / NHEADS, h = bh % NHEADS;
    const float* kb = K + ((size_t)bb * INNER + h * DH) * HWN;
    const float* vb = V + ((size_t)bb * INNER + h * DH) * HWN;
    __shared__ float kt[DH][64];
    __shared__ float vt[DH][65];
    int tid = threadIdx.x;
    int e = tid & 31;
    int d0 = tid >> 5;
    float acc[4] = {0.f, 0.f, 0.f, 0.f};
    for (int ch = 0; ch < 9; ++ch) {
        int n0 = seg * 576 + ch * 64;
        __syncthreads();
        #pragma unroll
        for (int j = 0; j < 8; ++j) {
            int idx = tid + 256 * j;
            int d = idx >> 6, nn = idx & 63;
            kt[d][nn] = kb[(size_t)d * HWN + n0 + nn];
            vt[d][nn] = vb[(size_t)d * HWN + n0 + nn];
        }
        __syncthreads();
        for (int nn = 0; nn < 64; ++nn) {
            float vv = vt[e][nn];
            #pragma unroll
            for (int i = 0; i < 4; ++i) acc[i] += kt[d0 + 8 * i][nn] * vv;
        }
    }
    #pragma unroll
    for (int i = 0; i < 4; ++i)
        ctxp[(((size_t)bh * 16 + seg) * DH + d0 + 8 * i) * DH + e] = acc[i];
}

// ---------------- reduce ctxp over segs and fold in 1/sum(exp(k)) per (b, d-channel) ------------
__global__ __launch_bounds__(256) void ctxreduce_kernel(const float* __restrict__ ctxp,
                                                        const float* __restrict__ Ssum,
                                                        int bo,
                                                        float* __restrict__ ctx) {
    int i = blockIdx.x * 256 + threadIdx.x;  // over GB*NHEADS*1024
    int bh = i >> 10, de = i & 1023;
    int d = de >> 5;
    int bb = bh / NHEADS, h = bh % NHEADS;
    float s = 0.f;
    #pragma unroll
    for (int seg = 0; seg < 16; ++seg) s += ctxp[((size_t)bh * 16 + seg) * 1024 + de];
    float S = Ssum[(bo + bb) * INNER + h * DH + d];
    ctx[i] = s / S;
}

// ---------------- fused q-softmax + q@ctx + silu, writes Oh/Ol [bb][n][INNER] bf16 hi/lo --------
__global__ __launch_bounds__(256) void qctx_kernel(const float* __restrict__ Q,
                                                   const float* __restrict__ ctx,
                                                   bf16_t* __restrict__ Oh,
                                                   bf16_t* __restrict__ Ol) {
    int bh = blockIdx.y;
    int bb = bh / NHEADS, h = bh % NHEADS;
    int n = blockIdx.x * 256 + threadIdx.x;
    __shared__ float cs[DH * DH];
    for (int j = threadIdx.x; j < DH * DH; j += 256) cs[j] = ctx[(size_t)bh * DH * DH + j];
    __syncthreads();
    const float* qb = Q + ((size_t)bb * INNER + h * DH) * HWN + n;
    float qv[DH];
    float mx = -1e30f;
    #pragma unroll
    for (int d = 0; d < DH; ++d) { qv[d] = qb[(size_t)d * HWN]; mx = fmaxf(mx, qv[d]); }
    float s = 0.f;
    #pragma unroll
    for (int d = 0; d < DH; ++d) { qv[d] = __expf(qv[d] - mx); s += qv[d]; }
    float inv = QSCALE / s;
    float acc[DH];
    #pragma unroll
    for (int e = 0; e < DH; ++e) acc[e] = 0.f;
    #pragma unroll
    for (int d = 0; d < DH; ++d) {
        float q = qv[d] * inv;
        #pragma unroll
        for (int e = 0; e < DH; ++e) acc[e] += q * cs[d * DH + e];
    }
    size_t ob = ((size_t)bb * HWN + n) * INNER + h * DH;
    bf16x8 hv, lv;
    #pragma unroll
    for (int e8 = 0; e8 < 4; ++e8) {
        #pragma unroll
        for (int e = 0; e < 8; ++e) {
            float x = acc[e8 * 8 + e];
            float sl = x / (1.0f + __expf(-x));   // silu
            bf16_t h = (bf16_t)sl;
            hv[e] = h;
            lv[e] = (bf16_t)(sl - (float)h);
        }
        *(bf16x8*)&Oh[ob + e8 * 8] = hv;
        *(bf16x8*)&Ol[ob + e8 * 8] = lv;
    }
}

// ---------------- final normalize, stats from S1o/S2o accumulated by conv2 epilogue -------------
// float4 vectorized: 4 consecutive n share (bb,c); HWN%4==0 so no boundary crossing.
__global__ __launch_bounds__(256) void norm_kernel(const float* __restrict__ X,
                                                   const float* __restrict__ S1,
                                                   const float* __restrict__ S2,
                                                   const float* __restrict__ g,
                                                   float* __restrict__ out,
                                                   int pbase) {
    size_t i = ((size_t)blockIdx.x * 256 + threadIdx.x) * 4;  // over GB*CDIM*HW
    int n = (int)(i % HWN);
    size_t bc = i / HWN;
    int c = (int)(bc % CDIM);
    int bb = (int)(bc / CDIM);
    int p = pbase + bb * HWN + n;
    f32x4 x  = *(const f32x4*)&X[i];
    f32x4 s1 = *(const f32x4*)&S1[p];
    f32x4 s2 = *(const f32x4*)&S2[p];
    float gc = g[c];
    f32x4 o;
    #pragma unroll
    for (int j = 0; j < 4; ++j) {
        float m = s1[j] * (1.0f / CDIM);
        float var = s2[j] * (1.0f / CDIM) - m * m;
        float rs = rsqrtf(var + EPSLN);
        o[j] = (x[j] - m) * rs * gc;
    }
    *(f32x4*)&out[i] = o;
}

extern "C" void kernel_launch(void* const* d_in, const int* in_sizes, int n_in,
                              void* d_out, int out_size, void* d_ws, size_t ws_size,
                              hipStream_t stream) {
    const float* fmap       = (const float*)d_in[0];
    const float* norm_g     = (const float*)d_in[1];
    const float* q_w1       = (const float*)d_in[2];
    const float* q_wd       = (const float*)d_in[3];
    const float* k_w1       = (const float*)d_in[4];
    const float* k_wd       = (const float*)d_in[5];
    const float* v_w1       = (const float*)d_in[6];
    const float* v_wd       = (const float*)d_in[7];
    const float* out_w      = (const float*)d_in[8];
    const float* out_norm_g = (const float*)d_in[9];
    float* out = (float*)d_out;

    float* ws = (float*)d_ws;
    size_t off = 0;
    auto alloc = [&](size_t n) { float* p = ws + off; off += n; return p; };
    // --- zeroed stats block (contiguous, one memset) ---
    float* S1   = alloc(73728);     // input-LN sum
    float* S2   = alloc(73728);     // input-LN sumsq
    float* S1o  = alloc(73728);     // output-LN sum (conv2 epilogue)
    float* S2o  = alloc(73728);     // output-LN sumsq
    float* Ssum = alloc(2048);      // per (b, inner-chan) sum of exp(k)
    const size_t ZERON = 73728ull * 4 + 2048;     // 296960 floats
    // --- rest ---
    float* wsum = alloc(768);
    bf16_t* WB  = (bf16_t*)alloc(393216);   // qkv weights, [3][hi/lo][131072] bf16
    bf16_t* OWB = (bf16_t*)alloc(131072);   // out_w, [hi/lo][131072] bf16
    float* ctxp = alloc(524288);
    float* ctx  = alloc(32768);
    bf16_t* Fh  = (bf16_t*)alloc(9437184);  // [GB][HWN][CDIM] bf16
    bf16_t* Fl  = (bf16_t*)alloc(9437184);
    float* A3   = alloc(3 * 9437184);       // [path][GB][INNER][HWN] fp32
    float* D3   = alloc(3 * 9437184);       // dwconv out (k-path holds exp)
    bf16_t* Oh  = (bf16_t*)alloc(4718592);  // [GB][HWN][INNER] bf16
    bf16_t* Ol  = (bf16_t*)alloc(4718592);
    float* CONV2 = alloc(18874368);         // [GB][CDIM][HWN] fp32
    // total: ~105.2M floats = 420.8 MB (ws is 576 MiB per harness fill size)

    dim3 blk(256);
    hipMemsetAsync(S1, 0, ZERON * sizeof(float), stream);
    wsum_kernel<<<dim3(3), blk, 0, stream>>>(q_w1, k_w1, v_w1, norm_g, wsum);
    wprep_kernel<<<dim3(2048), blk, 0, stream>>>(q_w1, k_w1, v_w1, norm_g, out_w, WB, OWB);

    for (int g = 0; g < 2; ++g) {
        const float* fmg = fmap + (size_t)g * GB * CDIM * HWN;
        int pbase = g * GB * HWN;
        int bo = g * GB;

        transpose_split_kernel<<<dim3(144, 8, GB), blk, 0, stream>>>(fmg, Fh, Fl, S1, S2, pbase);

        mfma_gemm_kernel<CDIM, INNER, 0><<<dim3(72, 6, GB), blk, 0, stream>>>(
            WB, Fh, Fl, S1, S2, wsum, pbase, A3);

        dwconv_kernel<<<dim3(HGT / 16, INNER, 3 * GB), dim3(24, 8), 0, stream>>>(
            A3, q_wd, k_wd, v_wd, D3, Ssum, bo);

        context_kernel<<<dim3(16, GB * NHEADS), blk, 0, stream>>>(
            D3 + PATHSZ, D3 + 2 * PATHSZ, ctxp);
        ctxreduce_kernel<<<dim3(GB * NHEADS * 1024 / 256), blk, 0, stream>>>(
            ctxp, Ssum, bo, ctx);
        qctx_kernel<<<dim3(HWN / 256, GB * NHEADS), blk, 0, stream>>>(D3, ctx, Oh, Ol);

        mfma_gemm_kernel<INNER, CDIM, 1><<<dim3(72, 4, GB), blk, 0, stream>>>(
            OWB, Oh, Ol, S1o, S2o, nullptr, pbase, CONV2);

        norm_kernel<<<dim3(GB * CDIM * HWN / 1024), blk, 0, stream>>>(
            CONV2, S1o, S2o, out_norm_g, out + (size_t)g * GB * CDIM * HWN, pbase);
    }
}